// Round 4
// baseline (845.712 us; speedup 1.0000x reference)
//
#include <hip/hip_runtime.h>
#include <cstdint>
#include <type_traits>

typedef uint16_t u16;
typedef uint32_t u32;
typedef __attribute__((ext_vector_type(4))) float f32x4;
typedef __attribute__((ext_vector_type(8))) __bf16 vbf8;
typedef __attribute__((ext_vector_type(8))) short vs8;

// ---- MFMA operand-type hedge: prefer v8bf16, fall back to v8i16 ----
template <typename T, typename = void>
struct CanMfma : std::false_type {};
template <typename T>
struct CanMfma<T, std::void_t<decltype(__builtin_amdgcn_mfma_f32_16x16x32_bf16(
    std::declval<T>(), std::declval<T>(), std::declval<f32x4>(), 0, 0, 0))>>
    : std::true_type {};
typedef std::conditional_t<CanMfma<vbf8>::value, vbf8, vs8> frag_t;

__device__ __forceinline__ f32x4 mfma_bf16(frag_t a, frag_t b, f32x4 c) {
  return __builtin_amdgcn_mfma_f32_16x16x32_bf16(a, b, c, 0, 0, 0);
}

__device__ __forceinline__ u16 f2bf(float f) {
  u32 u = __builtin_bit_cast(u32, f);
  u32 r = (u + 0x7FFFu + ((u >> 16) & 1u)) >> 16;
  return (u16)r;
}

__device__ __forceinline__ void gload_lds16(const void* g, void* l) {
  __builtin_amdgcn_global_load_lds(
      (const __attribute__((address_space(1))) void*)g,
      (__attribute__((address_space(3))) void*)l, 16, 0, 0);
}

#define VMW(n) asm volatile("s_waitcnt vmcnt(" #n ")" ::: "memory")
#define SB0() __builtin_amdgcn_sched_barrier(0)

// ---------------- cast fp32 -> bf16 ----------------
__global__ __launch_bounds__(256) void cast_f32_bf16(
    const float* __restrict__ in, u16* __restrict__ out, int n8) {
  int i = blockIdx.x * 256 + threadIdx.x;
  const int stride = gridDim.x * 256;
  for (; i < n8; i += stride) {
    const float4 a  = ((const float4*)in)[(size_t)i * 2];
    const float4 b2 = ((const float4*)in)[(size_t)i * 2 + 1];
    uint4 o;
    o.x = (u32)f2bf(a.x)  | ((u32)f2bf(a.y)  << 16);
    o.y = (u32)f2bf(a.z)  | ((u32)f2bf(a.w)  << 16);
    o.z = (u32)f2bf(b2.x) | ((u32)f2bf(b2.y) << 16);
    o.w = (u32)f2bf(b2.z) | ((u32)f2bf(b2.w) << 16);
    ((uint4*)out)[(size_t)i] = o;
  }
}

// ---------------- transpose + cast: in[K][N] f32 -> out[N][K] bf16 ----------------
__global__ __launch_bounds__(256) void transpose_cast(
    const float* __restrict__ in, u16* __restrict__ out, int K, int N) {
  __shared__ float tile[32][33];
  const int k0 = blockIdx.x * 32, n0 = blockIdx.y * 32;
  const int tr = threadIdx.x >> 5, tc = threadIdx.x & 31;
#pragma unroll
  for (int i = 0; i < 4; ++i)
    tile[tr + i * 8][tc] = in[(size_t)(k0 + tr + i * 8) * N + (n0 + tc)];
  __syncthreads();
#pragma unroll
  for (int i = 0; i < 4; ++i)
    out[(size_t)(n0 + tr + i * 8) * K + (k0 + tc)] = f2bf(tile[tc][tr + i * 8]);
}

// ---------------- small GEMM (128^2, 2-phase dbuf) for K/V projections ----------------
template <bool OUT_BF16>
__global__ __launch_bounds__(256) void gemm_bt(
    const u16* __restrict__ A, const u16* __restrict__ Bt,
    const float* __restrict__ bias, void* __restrict__ Cout,
    int M, int N, int K, int Mtiles, int Ntiles) {
  __shared__ char Al[2][128 * 32 * 2];
  __shared__ char Bl[2][128 * 32 * 2];

  const int nwg = Mtiles * Ntiles;
  int bid = (int)blockIdx.x;
  bid = (bid & 7) * (nwg >> 3) + (bid >> 3);
  const int mt = bid / Ntiles, nt = bid % Ntiles;
  const int m0 = mt * 128, n0 = nt * 128;

  const int tid = (int)threadIdx.x;
  const int lane = tid & 63;
  const int wv = tid >> 6;
  const int wm = wv & 1, wn = wv >> 1;
  const int lr = lane & 15, lg = lane >> 4;
  const int rsub = lane >> 2;
  const int slot = lane & 3;
  const int rb0 = n0 + rsub;

  auto stage = [&](int buf, int t) {
    const int k0 = t << 5;
#pragma unroll
    for (int c = 0; c < 2; ++c) {
      const int ci = c * 4 + wv;
      int rra = m0 + ci * 16 + rsub;
      if (rra >= M) rra = M - 1;
      gload_lds16(A + (size_t)rra * K + k0 + slot * 8, Al[buf] + ci * 1024);
      const int rrb = rb0 + ci * 16;
      gload_lds16(Bt + (size_t)rrb * K + k0 + slot * 8, Bl[buf] + ci * 1024);
    }
  };

  f32x4 zero4 = {0.f, 0.f, 0.f, 0.f};
  f32x4 acc[4][4];
#pragma unroll
  for (int i = 0; i < 4; ++i)
#pragma unroll
    for (int j = 0; j < 4; ++j) acc[i][j] = zero4;

  const int nk = K >> 5;
  int cur = 0;
  stage(0, 0);
  __syncthreads();

  for (int t = 0; t < nk; ++t) {
    if (t + 1 < nk) stage(cur ^ 1, t + 1);
    frag_t af[4], bf[4];
#pragma unroll
    for (int i = 0; i < 4; ++i) {
      af[i] = *(const frag_t*)(Al[cur] + (wm * 64 + i * 16 + lr) * 64 + lg * 16);
      bf[i] = *(const frag_t*)(Bl[cur] + (wn * 64 + i * 16 + lr) * 64 + lg * 16);
    }
#pragma unroll
    for (int i = 0; i < 4; ++i)
#pragma unroll
      for (int j = 0; j < 4; ++j)
        acc[i][j] = mfma_bf16(af[i], bf[j], acc[i][j]);
    __syncthreads();
    cur ^= 1;
  }

#pragma unroll
  for (int j = 0; j < 4; ++j) {
    const int col = n0 + wn * 64 + j * 16 + lr;
    const float bv = bias[col];
#pragma unroll
    for (int i = 0; i < 4; ++i) {
      const int rbase = m0 + wm * 64 + i * 16 + lg * 4;
#pragma unroll
      for (int r = 0; r < 4; ++r) {
        const int row = rbase + r;
        const float val = acc[i][j][r] + bv;
        if constexpr (OUT_BF16) {
          u32 me = f2bf(val);
          u32 other = __shfl_xor(me, 1);
          if ((lane & 1) == 0 && row < M) {
            *(u32*)((u16*)Cout + (size_t)row * N + col) = me | (other << 16);
          }
        } else {
          if (row < M) ((float*)Cout)[(size_t)row * N + col] = val;
        }
      }
    }
  }
}

// ---------------- big GEMM: 256^2 tile, BK=64, register-prefetch 4-phase pipeline ----
// Per phase: [stage gloads][ds_reads for NEXT phase][MFMA for THIS phase][gate][barrier].
// LDS pipe (next-phase reads) overlaps MFMA pipe (this phase). Gates (per-wave FIFO):
//   all 8 stage-gloads at P0 (order B0,B1,A0,A1); P1-end vmcnt(4) publishes B(t+1)
//   (read at P2); P2-end vmcnt(0) publishes A(t+1) (read at P3; loads 2 phases old).
// Cross-wave publish: every read is preceded by a barrier preceded by all waves' gate.
template <bool OUT_BF16>
__global__ __launch_bounds__(512) void gemm256(
    const u16* __restrict__ A, const u16* __restrict__ Bt,
    const float* __restrict__ bias, void* __restrict__ Cout,
    int M, int N, int K) {
  __shared__ u16 Al[2][256 * 64];
  __shared__ u16 Bl[2][256 * 64];

  const int Ntiles = N >> 8;
  const int nwg = (M >> 8) * Ntiles;
  int bid = (int)blockIdx.x;
  bid = (bid & 7) * (nwg >> 3) + (bid >> 3);  // bijective: nwg % 8 == 0
  const int mt = bid / Ntiles, ntl = bid % Ntiles;
  const int m0 = mt << 8, n0 = ntl << 8;

  const int tid = (int)threadIdx.x;
  const int lane = tid & 63;
  const int wid = tid >> 6;
  const int wm = wid >> 2, wn = wid & 3;  // 2 x 4 wave grid
  const int lr = lane & 15, lg = lane >> 4;
  const int lrx = lr & 7;

  // staging: wave stages chunks (wid*2, wid*2+1); 8 rows x 128B each, src pre-swizzled
  const int chunk = wid * 2;
  const int srow = lane >> 3;
  const int sslot = (lane & 7) ^ srow;
  const u16* Abase = A + (size_t)(m0 + chunk * 8 + srow) * K + sslot * 8;
  const u16* Bbase = Bt + (size_t)(n0 + chunk * 8 + srow) * K + sslot * 8;
  const int ldsChunkByte = (chunk * 8) * 128;

  auto stA = [&](u16* dst, int h, int t) {
    const u16* g = Abase + (size_t)(h << 7) * K + (t << 6);
    char* l = (char*)dst + (h << 14) + ldsChunkByte;
    gload_lds16(g, l);
    gload_lds16(g + ((size_t)K << 3), l + 1024);
  };
  auto stB = [&](u16* dst, int h, int t) {
    const u16* g = Bbase + (size_t)(h << 7) * K + (t << 6);
    char* l = (char*)dst + (h << 14) + ldsChunkByte;
    gload_lds16(g, l);
    gload_lds16(g + ((size_t)K << 3), l + 1024);
  };

  // swizzled ds_read of one 16B frag: logical slot = ks*4+lg, physical = logical^ (row&7)
  auto ldsF = [&](const u16* base, int row, int ks) -> frag_t {
    return *(const frag_t*)(base + (size_t)row * 64 + ((((ks) << 2) + lg) ^ lrx) * 8);
  };

  f32x4 zero4 = {0.f, 0.f, 0.f, 0.f};
  f32x4 acc[8][4];
#pragma unroll
  for (int i = 0; i < 8; ++i)
#pragma unroll
    for (int j = 0; j < 4; ++j) acc[i][j] = zero4;

  const int nt = K >> 6;  // K-tiles; even, >= 2
  const int ar0 = wm * 128 + lr;
  const int br0 = wn * 64 + lr;

  frag_t a0[4][2], a1[4][2], b0A[2][2], b0B[2][2], b1[2][2];

  auto rdA0 = [&](const u16* al) {
#pragma unroll
    for (int i = 0; i < 4; ++i) {
      a0[i][0] = ldsF(al, ar0 + i * 16, 0);
      a0[i][1] = ldsF(al, ar0 + i * 16, 1);
    }
  };
  auto rdA1 = [&](const u16* al) {
#pragma unroll
    for (int i = 0; i < 4; ++i) {
      a1[i][0] = ldsF(al, ar0 + 64 + i * 16, 0);
      a1[i][1] = ldsF(al, ar0 + 64 + i * 16, 1);
    }
  };
  auto rdB0 = [&](const u16* bl, frag_t (&d)[2][2]) {
#pragma unroll
    for (int j = 0; j < 2; ++j) {
      d[j][0] = ldsF(bl, br0 + j * 16, 0);
      d[j][1] = ldsF(bl, br0 + j * 16, 1);
    }
  };
  auto rdB1 = [&](const u16* bl) {
#pragma unroll
    for (int j = 0; j < 2; ++j) {
      b1[j][0] = ldsF(bl, br0 + 32 + j * 16, 0);
      b1[j][1] = ldsF(bl, br0 + 32 + j * 16, 1);
    }
  };
  auto mmaQ = [&](frag_t (&a)[4][2], frag_t (&b)[2][2], int io, int jo) {
    __builtin_amdgcn_s_setprio(1);
#pragma unroll
    for (int i = 0; i < 4; ++i)
#pragma unroll
      for (int j = 0; j < 2; ++j) {
        acc[io + i][jo + j] = mfma_bf16(a[i][0], b[j][0], acc[io + i][jo + j]);
        acc[io + i][jo + j] = mfma_bf16(a[i][1], b[j][1], acc[io + i][jo + j]);
      }
    __builtin_amdgcn_s_setprio(0);
  };

  // MFMA regs for tile t read 1+ phases earlier:
  //   a0(t): (t-1).P3   a1(t): t.P1   b0(t): (t-1).P2 (parity dbuf)   b1(t): t.P0
  auto tileStep = [&](const u16* al, const u16* bl, u16* alN, u16* blN,
                      frag_t (&b0c)[2][2], frag_t (&b0n)[2][2], int tN,
                      bool nl) {
    // ---- P0: stage all of tile t+1 (B first); prefetch b1(t); MFMA a0 x b0c
    if (nl) {
      stB(blN, 0, tN); stB(blN, 1, tN);
      stA(alN, 0, tN); stA(alN, 1, tN);
    }
    rdB1(bl);
    SB0();
    mmaQ(a0, b0c, 0, 0);
    SB0();
    __builtin_amdgcn_s_barrier();
    // ---- P1: prefetch a1(t); MFMA a0 x b1; gate publishes B(t+1)
    rdA1(al);
    SB0();
    mmaQ(a0, b1, 0, 2);
    SB0();
    if (nl) VMW(4);
    __builtin_amdgcn_s_barrier();
    // ---- P2: prefetch b0(t+1); MFMA a1 x b1; gate publishes A(t+1)
    if (nl) rdB0(blN, b0n);
    SB0();
    mmaQ(a1, b1, 4, 2);
    SB0();
    if (nl) VMW(0);
    __builtin_amdgcn_s_barrier();
    // ---- P3: prefetch a0(t+1); MFMA a1 x b0c
    if (nl) rdA0(alN);
    SB0();
    mmaQ(a1, b0c, 4, 0);
    SB0();
    __builtin_amdgcn_s_barrier();
  };

  // prologue: stage tile 0 fully, drain, publish, pre-read a0(0), b0(0)
  stB(&Bl[0][0], 0, 0); stB(&Bl[0][0], 1, 0);
  stA(&Al[0][0], 0, 0); stA(&Al[0][0], 1, 0);
  VMW(0);
  __builtin_amdgcn_s_barrier();
  rdA0(&Al[0][0]);
  rdB0(&Bl[0][0], b0A);

  for (int tt = 0; tt < nt; tt += 2) {
    tileStep(&Al[0][0], &Bl[0][0], &Al[1][0], &Bl[1][0], b0A, b0B, tt + 1,
             tt + 1 < nt);
    tileStep(&Al[1][0], &Bl[1][0], &Al[0][0], &Bl[0][0], b0B, b0A, tt + 2,
             tt + 2 < nt);
  }

  // epilogue: row = m0+wm*128+(ai>>2)*64+(ai&3)*16+lg*4+rr ; col = n0+wn*64+(bj>>1)*32+(bj&1)*16+lr
  float bvv[4];
#pragma unroll
  for (int bj = 0; bj < 4; ++bj)
    bvv[bj] = bias[n0 + wn * 64 + (bj >> 1) * 32 + (bj & 1) * 16 + lr];
#pragma unroll
  for (int ai = 0; ai < 8; ++ai) {
    const int rbase = m0 + wm * 128 + (ai >> 2) * 64 + (ai & 3) * 16 + lg * 4;
#pragma unroll
    for (int rr = 0; rr < 4; ++rr) {
      const int row = rbase + rr;
#pragma unroll
      for (int bj = 0; bj < 4; ++bj) {
        const int col = n0 + wn * 64 + (bj >> 1) * 32 + (bj & 1) * 16 + lr;
        const float val = acc[ai][bj][rr] + bvv[bj];
        if constexpr (OUT_BF16) {
          u32 me = f2bf(val);
          u32 other = __shfl_xor(me, 1);
          if ((lane & 1) == 0) {
            *(u32*)((u16*)Cout + (size_t)row * N + col) = me | (other << 16);
          }
        } else {
          ((float*)Cout)[(size_t)row * N + col] = val;
        }
      }
    }
  }
}

// ---------------- attention: per (b, h, 64 q-rows) block, 4 waves x 16 q-rows --------
__global__ __launch_bounds__(256) void attn_kernel(
    const u16* __restrict__ Q, const u16* __restrict__ K,
    const u16* __restrict__ V, u16* __restrict__ O) {
  __shared__ u16 Kl[96][72];
  __shared__ u16 Vt[64][104];

  const int bid = blockIdx.x;
  const int qt = bid & 63;
  const int h = (bid >> 6) & 15;
  const int b = bid >> 10;
  const int tid = threadIdx.x;

#pragma unroll
  for (int it = 0; it < 3; ++it) {
    const int idx = tid + it * 256;
    const int key = idx >> 3, s = idx & 7;
    uint4 val{0u, 0u, 0u, 0u};
    if (key < 77)
      val = *(const uint4*)(K + ((size_t)(b * 77 + key)) * 1024 + h * 64 + s * 8);
    *(uint4*)(&Kl[key][s * 8]) = val;
  }
#pragma unroll
  for (int it = 0; it < 3; ++it) {
    const int idx = tid + it * 256;
    if (idx < 616) {
      const int key = idx >> 3, s = idx & 7;
      const uint4 v4 =
          *(const uint4*)(V + ((size_t)(b * 77 + key)) * 1024 + h * 64 + s * 8);
      const u16* e = (const u16*)&v4;
#pragma unroll
      for (int j = 0; j < 8; ++j) Vt[s * 8 + j][key] = e[j];
    }
  }
#pragma unroll
  for (int it = 0; it < 5; ++it) {
    const int idx = tid + it * 256;
    if (idx < 1216) {
      const int d = idx / 19, kk = 77 + idx % 19;
      Vt[d][kk] = 0;
    }
  }
  __syncthreads();

  const int lane = tid & 63;
  const int wv = tid >> 6;
  const int lr = lane & 15;
  const int lg = lane >> 4;

  const size_t qrow = (size_t)(b * 4096 + qt * 64 + wv * 16 + lr) * 1024 + h * 64;
  frag_t qf[2];
#pragma unroll
  for (int ks = 0; ks < 2; ++ks)
    qf[ks] = *(const frag_t*)(Q + qrow + ks * 32 + lg * 8);

  f32x4 zero4 = {0.f, 0.f, 0.f, 0.f};
  f32x4 sa[5] = {zero4, zero4, zero4, zero4, zero4};
#pragma unroll
  for (int ks = 0; ks < 2; ++ks) {
#pragma unroll
    for (int kt = 0; kt < 5; ++kt) {
      frag_t kf = *(const frag_t*)(&Kl[kt * 16 + lr][ks * 32 + lg * 8]);
      sa[kt] = mfma_bf16(kf, qf[ks], sa[kt]);
    }
  }

  float p[5][4];
  float mx = -3.0e38f;
#pragma unroll
  for (int kt = 0; kt < 5; ++kt)
#pragma unroll
    for (int r = 0; r < 4; ++r) {
      const int key = kt * 16 + lg * 4 + r;
      float s = sa[kt][r] * 0.125f;
      if (key >= 77) s = -3.0e38f;
      p[kt][r] = s;
      mx = fmaxf(mx, s);
    }
  mx = fmaxf(mx, __shfl_xor(mx, 16));
  mx = fmaxf(mx, __shfl_xor(mx, 32));
  float sum = 0.f;
#pragma unroll
  for (int kt = 0; kt < 5; ++kt)
#pragma unroll
    for (int r = 0; r < 4; ++r) {
      const float e = __expf(p[kt][r] - mx);
      p[kt][r] = e;
      sum += e;
    }
  sum += __shfl_xor(sum, 16);
  sum += __shfl_xor(sum, 32);
  const float rden = 1.0f / sum;
#pragma unroll
  for (int kt = 0; kt < 5; ++kt)
#pragma unroll
    for (int r = 0; r < 4; ++r) p[kt][r] *= rden;

  union FP { frag_t v; u16 e[8]; };
  frag_t pa[3];
#pragma unroll
  for (int kb = 0; kb < 3; ++kb) {
    FP f;
#pragma unroll
    for (int j = 0; j < 8; ++j) {
      const int kt = 2 * kb + (j >> 2);
      f.e[j] = (kt < 5) ? f2bf(p[kt][j & 3]) : (u16)0;
    }
    pa[kb] = f.v;
  }

  f32x4 oa[4] = {zero4, zero4, zero4, zero4};
#pragma unroll
  for (int nt = 0; nt < 4; ++nt) {
    const int d = nt * 16 + lr;
#pragma unroll
    for (int kb = 0; kb < 3; ++kb) {
      const int key0 = kb * 32 + lg * 4;
      FP vb;
      *(uint2*)(&vb.e[0]) = *(const uint2*)(&Vt[d][key0]);
      *(uint2*)(&vb.e[4]) = *(const uint2*)(&Vt[d][key0 + 16]);
      oa[nt] = mfma_bf16(pa[kb], vb.v, oa[nt]);
    }
  }

#pragma unroll
  for (int nt = 0; nt < 4; ++nt)
#pragma unroll
    for (int r = 0; r < 4; ++r) {
      const int qr = wv * 16 + lg * 4 + r;
      u32 me = f2bf(oa[nt][r]);
      u32 other = __shfl_xor(me, 1);
      if ((lane & 1) == 0) {
        *(u32*)(O + ((size_t)(b * 4096 + qt * 64 + qr)) * 1024 + h * 64 +
                nt * 16 + lr) = me | (other << 16);
      }
    }
}

// ---------------- launch ----------------
extern "C" void kernel_launch(void* const* d_in, const int* in_sizes, int n_in,
                              void* d_out, int out_size, void* d_ws, size_t ws_size,
                              hipStream_t stream) {
  const float* x  = (const float*)d_in[0];
  const float* p  = (const float*)d_in[1];
  const float* Wq = (const float*)d_in[2];
  const float* bq = (const float*)d_in[3];
  const float* Wk = (const float*)d_in[4];
  const float* bk = (const float*)d_in[5];
  const float* Wv = (const float*)d_in[6];
  const float* bv = (const float*)d_in[7];
  const float* Ww = (const float*)d_in[8];
  const float* bw = (const float*)d_in[9];

  char* ws = (char*)d_ws;
  if (ws_size < 281034752ULL) return;

  u16* x_bf = (u16*)(ws + 0);          // 65536x1024 bf16; reused as attn_out
  u16* q_bf = (u16*)(ws + 134217728);  // 65536x1024
  u16* wq_t = (u16*)(ws + 268435456);  // [1024][1024]
  u16* ww_t = (u16*)(ws + 270532608);  // [1024][1024]
  u16* wk_t = (u16*)(ws + 272629760);  // [1024][512]
  u16* wv_t = (u16*)(ws + 273678336);  // [1024][512]
  u16* p_bf = (u16*)(ws + 274726912);  // 1232x512
  u16* k_bf = (u16*)(ws + 275988480);  // 1232x1024
  u16* v_bf = (u16*)(ws + 278511616);  // 1232x1024

  cast_f32_bf16<<<4096, 256, 0, stream>>>(x, x_bf, 8388608);
  cast_f32_bf16<<<308, 256, 0, stream>>>(p, p_bf, 78848);
  transpose_cast<<<dim3(32, 32), 256, 0, stream>>>(Wq, wq_t, 1024, 1024);
  transpose_cast<<<dim3(32, 32), 256, 0, stream>>>(Ww, ww_t, 1024, 1024);
  transpose_cast<<<dim3(16, 32), 256, 0, stream>>>(Wk, wk_t, 512, 1024);
  transpose_cast<<<dim3(16, 32), 256, 0, stream>>>(Wv, wv_t, 512, 1024);

  // K/V projections (small): 2-phase 128^2 kernel
  gemm_bt<true><<<80, 256, 0, stream>>>(p_bf, wk_t, bk, k_bf, 1232, 1024, 512, 10, 8);
  gemm_bt<true><<<80, 256, 0, stream>>>(p_bf, wv_t, bv, v_bf, 1232, 1024, 512, 10, 8);
  // Q projection: 256^2 register-prefetch kernel (1024 blocks)
  gemm256<true><<<1024, 512, 0, stream>>>(x_bf, wq_t, bq, q_bf, 65536, 1024, 1024);
  // attention
  attn_kernel<<<16384, 256, 0, stream>>>(q_bf, k_bf, v_bf, x_bf);
  // out projection -> fp32
  gemm256<false><<<1024, 512, 0, stream>>>(x_bf, ww_t, bw, d_out, 65536, 1024, 1024);
}

// Round 5
// 622.906 us; speedup vs baseline: 1.3577x; 1.3577x over previous
//
#include <hip/hip_runtime.h>
#include <cstdint>
#include <type_traits>

typedef uint16_t u16;
typedef uint32_t u32;
typedef __attribute__((ext_vector_type(4))) float f32x4;
typedef __attribute__((ext_vector_type(8))) __bf16 vbf8;
typedef __attribute__((ext_vector_type(8))) short vs8;

// ---- MFMA operand-type hedge: prefer v8bf16, fall back to v8i16 ----
template <typename T, typename = void>
struct CanMfma : std::false_type {};
template <typename T>
struct CanMfma<T, std::void_t<decltype(__builtin_amdgcn_mfma_f32_16x16x32_bf16(
    std::declval<T>(), std::declval<T>(), std::declval<f32x4>(), 0, 0, 0))>>
    : std::true_type {};
typedef std::conditional_t<CanMfma<vbf8>::value, vbf8, vs8> frag_t;

__device__ __forceinline__ f32x4 mfma_bf16(frag_t a, frag_t b, f32x4 c) {
  return __builtin_amdgcn_mfma_f32_16x16x32_bf16(a, b, c, 0, 0, 0);
}

__device__ __forceinline__ u16 f2bf(float f) {
  u32 u = __builtin_bit_cast(u32, f);
  u32 r = (u + 0x7FFFu + ((u >> 16) & 1u)) >> 16;
  return (u16)r;
}

__device__ __forceinline__ void gload_lds16(const void* g, void* l) {
  __builtin_amdgcn_global_load_lds(
      (const __attribute__((address_space(1))) void*)g,
      (__attribute__((address_space(3))) void*)l, 16, 0, 0);
}

// ---------------- cast fp32 -> bf16 ----------------
__global__ __launch_bounds__(256) void cast_f32_bf16(
    const float* __restrict__ in, u16* __restrict__ out, int n8) {
  int i = blockIdx.x * 256 + threadIdx.x;
  const int stride = gridDim.x * 256;
  for (; i < n8; i += stride) {
    const float4 a  = ((const float4*)in)[(size_t)i * 2];
    const float4 b2 = ((const float4*)in)[(size_t)i * 2 + 1];
    uint4 o;
    o.x = (u32)f2bf(a.x)  | ((u32)f2bf(a.y)  << 16);
    o.y = (u32)f2bf(a.z)  | ((u32)f2bf(a.w)  << 16);
    o.z = (u32)f2bf(b2.x) | ((u32)f2bf(b2.y) << 16);
    o.w = (u32)f2bf(b2.z) | ((u32)f2bf(b2.w) << 16);
    ((uint4*)out)[(size_t)i] = o;
  }
}

// ---------------- transpose + cast: in[K][N] f32 -> out[N][K] bf16 ----------------
__global__ __launch_bounds__(256) void transpose_cast(
    const float* __restrict__ in, u16* __restrict__ out, int K, int N) {
  __shared__ float tile[32][33];
  const int k0 = blockIdx.x * 32, n0 = blockIdx.y * 32;
  const int tr = threadIdx.x >> 5, tc = threadIdx.x & 31;
#pragma unroll
  for (int i = 0; i < 4; ++i)
    tile[tr + i * 8][tc] = in[(size_t)(k0 + tr + i * 8) * N + (n0 + tc)];
  __syncthreads();
#pragma unroll
  for (int i = 0; i < 4; ++i)
    out[(size_t)(n0 + tr + i * 8) * K + (k0 + tc)] = f2bf(tile[tc][tr + i * 8]);
}

// ---------------- small GEMM (128^2, 2-phase dbuf) for K/V projections ----------------
template <bool OUT_BF16>
__global__ __launch_bounds__(256) void gemm_bt(
    const u16* __restrict__ A, const u16* __restrict__ Bt,
    const float* __restrict__ bias, void* __restrict__ Cout,
    int M, int N, int K, int Mtiles, int Ntiles) {
  __shared__ char Al[2][128 * 32 * 2];
  __shared__ char Bl[2][128 * 32 * 2];

  const int nwg = Mtiles * Ntiles;
  int bid = (int)blockIdx.x;
  bid = (bid & 7) * (nwg >> 3) + (bid >> 3);
  const int mt = bid / Ntiles, nt = bid % Ntiles;
  const int m0 = mt * 128, n0 = nt * 128;

  const int tid = (int)threadIdx.x;
  const int lane = tid & 63;
  const int wv = tid >> 6;
  const int wm = wv & 1, wn = wv >> 1;
  const int lr = lane & 15, lg = lane >> 4;
  const int rsub = lane >> 2;
  const int slot = lane & 3;
  const int rb0 = n0 + rsub;

  auto stage = [&](int buf, int t) {
    const int k0 = t << 5;
#pragma unroll
    for (int c = 0; c < 2; ++c) {
      const int ci = c * 4 + wv;
      int rra = m0 + ci * 16 + rsub;
      if (rra >= M) rra = M - 1;
      gload_lds16(A + (size_t)rra * K + k0 + slot * 8, Al[buf] + ci * 1024);
      const int rrb = rb0 + ci * 16;
      gload_lds16(Bt + (size_t)rrb * K + k0 + slot * 8, Bl[buf] + ci * 1024);
    }
  };

  f32x4 zero4 = {0.f, 0.f, 0.f, 0.f};
  f32x4 acc[4][4];
#pragma unroll
  for (int i = 0; i < 4; ++i)
#pragma unroll
    for (int j = 0; j < 4; ++j) acc[i][j] = zero4;

  const int nk = K >> 5;
  int cur = 0;
  stage(0, 0);
  __syncthreads();

  for (int t = 0; t < nk; ++t) {
    if (t + 1 < nk) stage(cur ^ 1, t + 1);
    frag_t af[4], bf[4];
#pragma unroll
    for (int i = 0; i < 4; ++i) {
      af[i] = *(const frag_t*)(Al[cur] + (wm * 64 + i * 16 + lr) * 64 + lg * 16);
      bf[i] = *(const frag_t*)(Bl[cur] + (wn * 64 + i * 16 + lr) * 64 + lg * 16);
    }
#pragma unroll
    for (int i = 0; i < 4; ++i)
#pragma unroll
      for (int j = 0; j < 4; ++j)
        acc[i][j] = mfma_bf16(af[i], bf[j], acc[i][j]);
    __syncthreads();
    cur ^= 1;
  }

#pragma unroll
  for (int j = 0; j < 4; ++j) {
    const int col = n0 + wn * 64 + j * 16 + lr;
    const float bv = bias[col];
#pragma unroll
    for (int i = 0; i < 4; ++i) {
      const int rbase = m0 + wm * 64 + i * 16 + lg * 4;
#pragma unroll
      for (int r = 0; r < 4; ++r) {
        const int row = rbase + r;
        const float val = acc[i][j][r] + bv;
        if constexpr (OUT_BF16) {
          u32 me = f2bf(val);
          u32 other = __shfl_xor(me, 1);
          if ((lane & 1) == 0 && row < M) {
            *(u32*)((u16*)Cout + (size_t)row * N + col) = me | (other << 16);
          }
        } else {
          if (row < M) ((float*)Cout)[(size_t)row * N + col] = val;
        }
      }
    }
  }
}

// ---------------- big GEMM: 256^2 tile, BK=64, single-region 2-phase ----------------
// Evidence base: m230/m248/m112 (2ph 256^2 = 655-792 TF). ONE barrier + ONE vmcnt(0)
// per K-tile; the vmcnt(0) drains loads issued a full tile (~2400cyc) earlier -> free.
// No intra-tile barriers: compiler interleaves 24 ds_reads with 64 MFMAs (fine lgkmcnt),
// waves drift -> cross-wave LDS/MFMA overlap (m114). T2 source-preswizzle kept
// (conflicts=0 measured), XCD swizzle kept. M,N mult of 256; K mult of 128.
template <bool OUT_BF16>
__global__ __launch_bounds__(512) void gemm256(
    const u16* __restrict__ A, const u16* __restrict__ Bt,
    const float* __restrict__ bias, void* __restrict__ Cout,
    int M, int N, int K) {
  __shared__ u16 Al[2][256 * 64];
  __shared__ u16 Bl[2][256 * 64];

  const int Ntiles = N >> 8;
  const int nwg = (M >> 8) * Ntiles;
  int bid = (int)blockIdx.x;
  bid = (bid & 7) * (nwg >> 3) + (bid >> 3);  // bijective: nwg % 8 == 0
  const int mt = bid / Ntiles, ntl = bid % Ntiles;
  const int m0 = mt << 8, n0 = ntl << 8;

  const int tid = (int)threadIdx.x;
  const int lane = tid & 63;
  const int wid = tid >> 6;
  const int wm = wid >> 2, wn = wid & 3;  // 2 x 4 wave grid
  const int lr = lane & 15, lg = lane >> 4;
  const int lrx = lr & 7;

  // staging: wave stages chunks (wid*2, wid*2+1); 8 rows x 128B per gload,
  // source pre-swizzled (rule 21) so linear LDS dest + swizzled ds_read match.
  const int chunk = wid * 2;
  const int srow = lane >> 3;
  const int sslot = (lane & 7) ^ srow;
  const u16* Abase = A + (size_t)(m0 + chunk * 8 + srow) * K + sslot * 8;
  const u16* Bbase = Bt + (size_t)(n0 + chunk * 8 + srow) * K + sslot * 8;
  const int ldsChunkByte = (chunk * 8) * 128;

  auto stA = [&](u16* dst, int h, int t) {
    const u16* g = Abase + (size_t)(h << 7) * K + (t << 6);
    char* l = (char*)dst + (h << 14) + ldsChunkByte;
    gload_lds16(g, l);
    gload_lds16(g + ((size_t)K << 3), l + 1024);
  };
  auto stB = [&](u16* dst, int h, int t) {
    const u16* g = Bbase + (size_t)(h << 7) * K + (t << 6);
    char* l = (char*)dst + (h << 14) + ldsChunkByte;
    gload_lds16(g, l);
    gload_lds16(g + ((size_t)K << 3), l + 1024);
  };

  // swizzled ds_read of one 16B frag: logical slot = ks*4+lg, phys = logical^(row&7)
  auto ldsF = [&](const u16* base, int row, int ks) -> frag_t {
    return *(const frag_t*)(base + (size_t)row * 64 + ((((ks) << 2) + lg) ^ lrx) * 8);
  };

  f32x4 zero4 = {0.f, 0.f, 0.f, 0.f};
  f32x4 acc[8][4];
#pragma unroll
  for (int i = 0; i < 8; ++i)
#pragma unroll
    for (int j = 0; j < 4; ++j) acc[i][j] = zero4;

  const int nt = K >> 6;  // K-tiles, >= 2
  const int ar0 = wm * 128 + lr;
  const int br0 = wn * 64 + lr;

  // prologue: stage tiles 0 and 1; wait only tile 0 (vmcnt(8) keeps tile 1 in flight)
  stB(&Bl[0][0], 0, 0); stB(&Bl[0][0], 1, 0);
  stA(&Al[0][0], 0, 0); stA(&Al[0][0], 1, 0);
  stB(&Bl[1][0], 0, 1); stB(&Bl[1][0], 1, 1);
  stA(&Al[1][0], 0, 1); stA(&Al[1][0], 1, 1);
  asm volatile("s_waitcnt vmcnt(8)" ::: "memory");
  __builtin_amdgcn_s_barrier();

  for (int t = 0; t < nt; ++t) {
    const int cur = t & 1;
    const u16* al = &Al[cur][0];
    const u16* bl = &Bl[cur][0];
    // stage tile t+1 into the buffer consumed at t-1 (safe: fully read, barrier passed)
    if (t >= 1 && t + 1 < nt) {
      u16* alN = &Al[cur ^ 1][0];
      u16* blN = &Bl[cur ^ 1][0];
      stB(blN, 0, t + 1); stB(blN, 1, t + 1);
      stA(alN, 0, t + 1); stA(alN, 1, t + 1);
    }
    // single scheduling region: 24 ds_reads + 64 MFMA, compiler interleaves
#pragma unroll
    for (int ks = 0; ks < 2; ++ks) {
      frag_t a[8], b[4];
#pragma unroll
      for (int i = 0; i < 8; ++i) a[i] = ldsF(al, ar0 + i * 16, ks);
#pragma unroll
      for (int j = 0; j < 4; ++j) b[j] = ldsF(bl, br0 + j * 16, ks);
#pragma unroll
      for (int i = 0; i < 8; ++i)
#pragma unroll
        for (int j = 0; j < 4; ++j)
          acc[i][j] = mfma_bf16(a[i], b[j], acc[i][j]);
    }
    if (t + 1 < nt) {
      // drains stage(t+1), issued one full tile ago (> HBM latency) -> near-free
      asm volatile("s_waitcnt vmcnt(0)" ::: "memory");
      __builtin_amdgcn_s_barrier();
    }
  }

  // epilogue: row = m0+wm*128+ai*16+lg*4+rr ; col = n0+wn*64+bj*16+lr
  // pack via xor(1)+xor(2) -> contiguous 8B (bf16) / 16B (fp32) stores on lane%4==0
  float bvv[4];
#pragma unroll
  for (int bj = 0; bj < 4; ++bj) bvv[bj] = bias[n0 + wn * 64 + bj * 16 + lr];
#pragma unroll
  for (int ai = 0; ai < 8; ++ai) {
    const int rbase = m0 + wm * 128 + ai * 16 + lg * 4;
#pragma unroll
    for (int rr = 0; rr < 4; ++rr) {
      const int row = rbase + rr;
#pragma unroll
      for (int bj = 0; bj < 4; ++bj) {
        const int cb = n0 + wn * 64 + bj * 16;  // lane's col = cb + lr
        const float val = acc[ai][bj][rr] + bvv[bj];
        if constexpr (OUT_BF16) {
          u32 me = f2bf(val);
          u32 d0 = me | (__shfl_xor(me, 1) << 16);  // even lanes: cols (lr, lr+1)
          u32 d1 = __shfl_xor(d0, 2);               // lanes lr%4==0: cols (lr+2, lr+3)
          if ((lane & 3) == 0) {
            uint2 o; o.x = d0; o.y = d1;
            *(uint2*)((u16*)Cout + (size_t)row * N + cb + (lr & 12)) = o;
          }
        } else {
          float v0 = val;
          float v1 = __shfl_xor(v0, 1);  // even lanes: cols (lr, lr+1)
          float v2 = __shfl_xor(v0, 2);
          float v3 = __shfl_xor(v1, 2);  // lanes lr%4==0: cols (lr+2, lr+3)
          if ((lane & 3) == 0) {
            float4 o; o.x = v0; o.y = v1; o.z = v2; o.w = v3;
            *(float4*)((float*)Cout + (size_t)row * N + cb + (lr & 12)) = o;
          }
        }
      }
    }
  }
}

// ---------------- attention (unchanged, passing) ----------------
__global__ __launch_bounds__(256) void attn_kernel(
    const u16* __restrict__ Q, const u16* __restrict__ K,
    const u16* __restrict__ V, u16* __restrict__ O) {
  __shared__ u16 Kl[96][72];
  __shared__ u16 Vt[64][104];

  const int bid = blockIdx.x;
  const int qt = bid & 63;
  const int h = (bid >> 6) & 15;
  const int b = bid >> 10;
  const int tid = threadIdx.x;

#pragma unroll
  for (int it = 0; it < 3; ++it) {
    const int idx = tid + it * 256;
    const int key = idx >> 3, s = idx & 7;
    uint4 val{0u, 0u, 0u, 0u};
    if (key < 77)
      val = *(const uint4*)(K + ((size_t)(b * 77 + key)) * 1024 + h * 64 + s * 8);
    *(uint4*)(&Kl[key][s * 8]) = val;
  }
#pragma unroll
  for (int it = 0; it < 3; ++it) {
    const int idx = tid + it * 256;
    if (idx < 616) {
      const int key = idx >> 3, s = idx & 7;
      const uint4 v4 =
          *(const uint4*)(V + ((size_t)(b * 77 + key)) * 1024 + h * 64 + s * 8);
      const u16* e = (const u16*)&v4;
#pragma unroll
      for (int j = 0; j < 8; ++j) Vt[s * 8 + j][key] = e[j];
    }
  }
#pragma unroll
  for (int it = 0; it < 5; ++it) {
    const int idx = tid + it * 256;
    if (idx < 1216) {
      const int d = idx / 19, kk = 77 + idx % 19;
      Vt[d][kk] = 0;
    }
  }
  __syncthreads();

  const int lane = tid & 63;
  const int wv = tid >> 6;
  const int lr = lane & 15;
  const int lg = lane >> 4;

  const size_t qrow = (size_t)(b * 4096 + qt * 64 + wv * 16 + lr) * 1024 + h * 64;
  frag_t qf[2];
#pragma unroll
  for (int ks = 0; ks < 2; ++ks)
    qf[ks] = *(const frag_t*)(Q + qrow + ks * 32 + lg * 8);

  f32x4 zero4 = {0.f, 0.f, 0.f, 0.f};
  f32x4 sa[5] = {zero4, zero4, zero4, zero4, zero4};
#pragma unroll
  for (int ks = 0; ks < 2; ++ks) {
#pragma unroll
    for (int kt = 0; kt < 5; ++kt) {
      frag_t kf = *(const frag_t*)(&Kl[kt * 16 + lr][ks * 32 + lg * 8]);
      sa[kt] = mfma_bf16(kf, qf[ks], sa[kt]);
    }
  }

  float p[5][4];
  float mx = -3.0e38f;
#pragma unroll
  for (int kt = 0; kt < 5; ++kt)
#pragma unroll
    for (int r = 0; r < 4; ++r) {
      const int key = kt * 16 + lg * 4 + r;
      float s = sa[kt][r] * 0.125f;
      if (key >= 77) s = -3.0e38f;
      p[kt][r] = s;
      mx = fmaxf(mx, s);
    }
  mx = fmaxf(mx, __shfl_xor(mx, 16));
  mx = fmaxf(mx, __shfl_xor(mx, 32));
  float sum = 0.f;
#pragma unroll
  for (int kt = 0; kt < 5; ++kt)
#pragma unroll
    for (int r = 0; r < 4; ++r) {
      const float e = __expf(p[kt][r] - mx);
      p[kt][r] = e;
      sum += e;
    }
  sum += __shfl_xor(sum, 16);
  sum += __shfl_xor(sum, 32);
  const float rden = 1.0f / sum;
#pragma unroll
  for (int kt = 0; kt < 5; ++kt)
#pragma unroll
    for (int r = 0; r < 4; ++r) p[kt][r] *= rden;

  union FP { frag_t v; u16 e[8]; };
  frag_t pa[3];
#pragma unroll
  for (int kb = 0; kb < 3; ++kb) {
    FP f;
#pragma unroll
    for (int j = 0; j < 8; ++j) {
      const int kt = 2 * kb + (j >> 2);
      f.e[j] = (kt < 5) ? f2bf(p[kt][j & 3]) : (u16)0;
    }
    pa[kb] = f.v;
  }

  f32x4 oa[4] = {zero4, zero4, zero4, zero4};
#pragma unroll
  for (int nt = 0; nt < 4; ++nt) {
    const int d = nt * 16 + lr;
#pragma unroll
    for (int kb = 0; kb < 3; ++kb) {
      const int key0 = kb * 32 + lg * 4;
      FP vb;
      *(uint2*)(&vb.e[0]) = *(const uint2*)(&Vt[d][key0]);
      *(uint2*)(&vb.e[4]) = *(const uint2*)(&Vt[d][key0 + 16]);
      oa[nt] = mfma_bf16(pa[kb], vb.v, oa[nt]);
    }
  }

#pragma unroll
  for (int nt = 0; nt < 4; ++nt)
#pragma unroll
    for (int r = 0; r < 4; ++r) {
      const int qr = wv * 16 + lg * 4 + r;
      u32 me = f2bf(oa[nt][r]);
      u32 other = __shfl_xor(me, 1);
      if ((lane & 1) == 0) {
        *(u32*)(O + ((size_t)(b * 4096 + qt * 64 + qr)) * 1024 + h * 64 +
                nt * 16 + lr) = me | (other << 16);
      }
    }
}

// ---------------- launch ----------------
extern "C" void kernel_launch(void* const* d_in, const int* in_sizes, int n_in,
                              void* d_out, int out_size, void* d_ws, size_t ws_size,
                              hipStream_t stream) {
  const float* x  = (const float*)d_in[0];
  const float* p  = (const float*)d_in[1];
  const float* Wq = (const float*)d_in[2];
  const float* bq = (const float*)d_in[3];
  const float* Wk = (const float*)d_in[4];
  const float* bk = (const float*)d_in[5];
  const float* Wv = (const float*)d_in[6];
  const float* bv = (const float*)d_in[7];
  const float* Ww = (const float*)d_in[8];
  const float* bw = (const float*)d_in[9];

  char* ws = (char*)d_ws;
  if (ws_size < 281034752ULL) return;

  u16* x_bf = (u16*)(ws + 0);          // 65536x1024 bf16; reused as attn_out
  u16* q_bf = (u16*)(ws + 134217728);  // 65536x1024
  u16* wq_t = (u16*)(ws + 268435456);  // [1024][1024]
  u16* ww_t = (u16*)(ws + 270532608);  // [1024][1024]
  u16* wk_t = (u16*)(ws + 272629760);  // [1024][512]
  u16* wv_t = (u16*)(ws + 273678336);  // [1024][512]
  u16* p_bf = (u16*)(ws + 274726912);  // 1232x512
  u16* k_bf = (u16*)(ws + 275988480);  // 1232x1024
  u16* v_bf = (u16*)(ws + 278511616);  // 1232x1024

  cast_f32_bf16<<<4096, 256, 0, stream>>>(x, x_bf, 8388608);
  cast_f32_bf16<<<308, 256, 0, stream>>>(p, p_bf, 78848);
  transpose_cast<<<dim3(32, 32), 256, 0, stream>>>(Wq, wq_t, 1024, 1024);
  transpose_cast<<<dim3(32, 32), 256, 0, stream>>>(Ww, ww_t, 1024, 1024);
  transpose_cast<<<dim3(16, 32), 256, 0, stream>>>(Wk, wk_t, 512, 1024);
  transpose_cast<<<dim3(16, 32), 256, 0, stream>>>(Wv, wv_t, 512, 1024);

  // K/V projections (small): 2-phase 128^2 kernel
  gemm_bt<true><<<80, 256, 0, stream>>>(p_bf, wk_t, bk, k_bf, 1232, 1024, 512, 10, 8);
  gemm_bt<true><<<80, 256, 0, stream>>>(p_bf, wv_t, bv, v_bf, 1232, 1024, 512, 10, 8);
  // Q projection: 256^2 single-region 2-phase kernel (1024 blocks)
  gemm256<true><<<1024, 512, 0, stream>>>(x_bf, wq_t, bq, q_bf, 65536, 1024, 1024);
  // attention
  attn_kernel<<<16384, 256, 0, stream>>>(q_bf, k_bf, v_bf, x_bf);
  // out projection -> fp32
  gemm256<false><<<1024, 512, 0, stream>>>(x_bf, ww_t, bw, d_out, 65536, 1024, 1024);
}

// Round 6
// 618.526 us; speedup vs baseline: 1.3673x; 1.0071x over previous
//
#include <hip/hip_runtime.h>
#include <cstdint>
#include <type_traits>

typedef uint16_t u16;
typedef uint32_t u32;
typedef __attribute__((ext_vector_type(4))) float f32x4;
typedef __attribute__((ext_vector_type(16))) float f32x16;
typedef __attribute__((ext_vector_type(8))) __bf16 vbf8;
typedef __attribute__((ext_vector_type(8))) short vs8;

// ---- MFMA operand-type hedge: prefer v8bf16, fall back to v8i16 ----
template <typename T, typename = void>
struct CanMfma : std::false_type {};
template <typename T>
struct CanMfma<T, std::void_t<decltype(__builtin_amdgcn_mfma_f32_16x16x32_bf16(
    std::declval<T>(), std::declval<T>(), std::declval<f32x4>(), 0, 0, 0))>>
    : std::true_type {};
typedef std::conditional_t<CanMfma<vbf8>::value, vbf8, vs8> frag_t;

template <typename T, typename = void>
struct CanMfma32 : std::false_type {};
template <typename T>
struct CanMfma32<T, std::void_t<decltype(__builtin_amdgcn_mfma_f32_32x32x16_bf16(
    std::declval<T>(), std::declval<T>(), std::declval<f32x16>(), 0, 0, 0))>>
    : std::true_type {};
typedef std::conditional_t<CanMfma32<vbf8>::value, vbf8, vs8> frag32_t;

__device__ __forceinline__ f32x4 mfma_bf16(frag_t a, frag_t b, f32x4 c) {
  return __builtin_amdgcn_mfma_f32_16x16x32_bf16(a, b, c, 0, 0, 0);
}
__device__ __forceinline__ f32x16 mfma32_bf16(frag32_t a, frag32_t b, f32x16 c) {
  return __builtin_amdgcn_mfma_f32_32x32x16_bf16(a, b, c, 0, 0, 0);
}

__device__ __forceinline__ u16 f2bf(float f) {
  u32 u = __builtin_bit_cast(u32, f);
  u32 r = (u + 0x7FFFu + ((u >> 16) & 1u)) >> 16;
  return (u16)r;
}

__device__ __forceinline__ void gload_lds16(const void* g, void* l) {
  __builtin_amdgcn_global_load_lds(
      (const __attribute__((address_space(1))) void*)g,
      (__attribute__((address_space(3))) void*)l, 16, 0, 0);
}

// ---------------- cast fp32 -> bf16 ----------------
__global__ __launch_bounds__(256) void cast_f32_bf16(
    const float* __restrict__ in, u16* __restrict__ out, int n8) {
  int i = blockIdx.x * 256 + threadIdx.x;
  const int stride = gridDim.x * 256;
  for (; i < n8; i += stride) {
    const float4 a  = ((const float4*)in)[(size_t)i * 2];
    const float4 b2 = ((const float4*)in)[(size_t)i * 2 + 1];
    uint4 o;
    o.x = (u32)f2bf(a.x)  | ((u32)f2bf(a.y)  << 16);
    o.y = (u32)f2bf(a.z)  | ((u32)f2bf(a.w)  << 16);
    o.z = (u32)f2bf(b2.x) | ((u32)f2bf(b2.y) << 16);
    o.w = (u32)f2bf(b2.z) | ((u32)f2bf(b2.w) << 16);
    ((uint4*)out)[(size_t)i] = o;
  }
}

// ---------------- transpose + cast: in[K][N] f32 -> out[N][K] bf16 ----------------
__global__ __launch_bounds__(256) void transpose_cast(
    const float* __restrict__ in, u16* __restrict__ out, int K, int N) {
  __shared__ float tile[32][33];
  const int k0 = blockIdx.x * 32, n0 = blockIdx.y * 32;
  const int tr = threadIdx.x >> 5, tc = threadIdx.x & 31;
#pragma unroll
  for (int i = 0; i < 4; ++i)
    tile[tr + i * 8][tc] = in[(size_t)(k0 + tr + i * 8) * N + (n0 + tc)];
  __syncthreads();
#pragma unroll
  for (int i = 0; i < 4; ++i)
    out[(size_t)(n0 + tr + i * 8) * K + (k0 + tc)] = f2bf(tile[tc][tr + i * 8]);
}

// ---------------- small GEMM (128^2, 2-phase dbuf) for K/V projections ----------------
template <bool OUT_BF16>
__global__ __launch_bounds__(256) void gemm_bt(
    const u16* __restrict__ A, const u16* __restrict__ Bt,
    const float* __restrict__ bias, void* __restrict__ Cout,
    int M, int N, int K, int Mtiles, int Ntiles) {
  __shared__ char Al[2][128 * 32 * 2];
  __shared__ char Bl[2][128 * 32 * 2];

  const int nwg = Mtiles * Ntiles;
  int bid = (int)blockIdx.x;
  bid = (bid & 7) * (nwg >> 3) + (bid >> 3);
  const int mt = bid / Ntiles, nt = bid % Ntiles;
  const int m0 = mt * 128, n0 = nt * 128;

  const int tid = (int)threadIdx.x;
  const int lane = tid & 63;
  const int wv = tid >> 6;
  const int wm = wv & 1, wn = wv >> 1;
  const int lr = lane & 15, lg = lane >> 4;
  const int rsub = lane >> 2;
  const int slot = lane & 3;
  const int rb0 = n0 + rsub;

  auto stage = [&](int buf, int t) {
    const int k0 = t << 5;
#pragma unroll
    for (int c = 0; c < 2; ++c) {
      const int ci = c * 4 + wv;
      int rra = m0 + ci * 16 + rsub;
      if (rra >= M) rra = M - 1;
      gload_lds16(A + (size_t)rra * K + k0 + slot * 8, Al[buf] + ci * 1024);
      const int rrb = rb0 + ci * 16;
      gload_lds16(Bt + (size_t)rrb * K + k0 + slot * 8, Bl[buf] + ci * 1024);
    }
  };

  f32x4 zero4 = {0.f, 0.f, 0.f, 0.f};
  f32x4 acc[4][4];
#pragma unroll
  for (int i = 0; i < 4; ++i)
#pragma unroll
    for (int j = 0; j < 4; ++j) acc[i][j] = zero4;

  const int nk = K >> 5;
  int cur = 0;
  stage(0, 0);
  __syncthreads();

  for (int t = 0; t < nk; ++t) {
    if (t + 1 < nk) stage(cur ^ 1, t + 1);
    frag_t af[4], bf[4];
#pragma unroll
    for (int i = 0; i < 4; ++i) {
      af[i] = *(const frag_t*)(Al[cur] + (wm * 64 + i * 16 + lr) * 64 + lg * 16);
      bf[i] = *(const frag_t*)(Bl[cur] + (wn * 64 + i * 16 + lr) * 64 + lg * 16);
    }
#pragma unroll
    for (int i = 0; i < 4; ++i)
#pragma unroll
      for (int j = 0; j < 4; ++j)
        acc[i][j] = mfma_bf16(af[i], bf[j], acc[i][j]);
    __syncthreads();
    cur ^= 1;
  }

#pragma unroll
  for (int j = 0; j < 4; ++j) {
    const int col = n0 + wn * 64 + j * 16 + lr;
    const float bv = bias[col];
#pragma unroll
    for (int i = 0; i < 4; ++i) {
      const int rbase = m0 + wm * 64 + i * 16 + lg * 4;
#pragma unroll
      for (int r = 0; r < 4; ++r) {
        const int row = rbase + r;
        const float val = acc[i][j][r] + bv;
        if constexpr (OUT_BF16) {
          u32 me = f2bf(val);
          u32 other = __shfl_xor(me, 1);
          if ((lane & 1) == 0 && row < M) {
            *(u32*)((u16*)Cout + (size_t)row * N + col) = me | (other << 16);
          }
        } else {
          if (row < M) ((float*)Cout)[(size_t)row * N + col] = val;
        }
      }
    }
  }
}

// ---------------- big GEMM: 256^2, BK=64, single-region 2-phase, 32x32x16 MFMA ------
// Same proven sync structure as R4 (ONE vmcnt(0)+barrier per K-tile). MFMA switched
// to 32x32x16: same FLOPs in 20% fewer matrix-pipe cycles (m119: 2495 vs 2075 TF),
// half the MFMA instructions; identical ds_read count/bytes. A/B frag: 16B contiguous
// at k-slot (lane>>5); any within-lane k-permutation cancels (A,B share the formula).
// C/D (m74/m101): col = lane&31, row = (r&3) + 8*(r>>2) + 4*(lane>>5).
template <bool OUT_BF16>
__global__ __launch_bounds__(512) void gemm256(
    const u16* __restrict__ A, const u16* __restrict__ Bt,
    const float* __restrict__ bias, void* __restrict__ Cout,
    int M, int N, int K) {
  __shared__ u16 Al[2][256 * 64];
  __shared__ u16 Bl[2][256 * 64];

  const int Ntiles = N >> 8;
  const int nwg = (M >> 8) * Ntiles;
  int bid = (int)blockIdx.x;
  bid = (bid & 7) * (nwg >> 3) + (bid >> 3);  // bijective: nwg % 8 == 0
  const int mt = bid / Ntiles, ntl = bid % Ntiles;
  const int m0 = mt << 8, n0 = ntl << 8;

  const int tid = (int)threadIdx.x;
  const int lane = tid & 63;
  const int wid = tid >> 6;
  const int wm = wid >> 2, wn = wid & 3;  // 2 x 4 wave grid, wave tile 128x64
  const int l31 = lane & 31;
  const int lhalf = lane >> 5;

  // staging: wave stages chunks (wid*2, wid*2+1); 8 rows x 128B per gload,
  // source pre-swizzled (rule 21) so linear LDS dest + swizzled ds_read match.
  const int chunk = wid * 2;
  const int srow = lane >> 3;
  const int sslot = (lane & 7) ^ srow;
  const u16* Abase = A + (size_t)(m0 + chunk * 8 + srow) * K + sslot * 8;
  const u16* Bbase = Bt + (size_t)(n0 + chunk * 8 + srow) * K + sslot * 8;
  const int ldsChunkByte = (chunk * 8) * 128;

  auto stA = [&](u16* dst, int h, int t) {
    const u16* g = Abase + (size_t)(h << 7) * K + (t << 6);
    char* l = (char*)dst + (h << 14) + ldsChunkByte;
    gload_lds16(g, l);
    gload_lds16(g + ((size_t)K << 3), l + 1024);
  };
  auto stB = [&](u16* dst, int h, int t) {
    const u16* g = Bbase + (size_t)(h << 7) * K + (t << 6);
    char* l = (char*)dst + (h << 14) + ldsChunkByte;
    gload_lds16(g, l);
    gload_lds16(g + ((size_t)K << 3), l + 1024);
  };

  // swizzled ds_read of one 16B frag: logical slot = ks*2 + (lane>>5),
  // physical = logical ^ (row&7). row in [0,256).
  auto ldsF = [&](const u16* base, int row, int ks) -> frag32_t {
    const int slot = ((ks << 1) + lhalf) ^ (row & 7);
    return *(const frag32_t*)(base + (size_t)row * 64 + slot * 8);
  };

  f32x16 acc[4][2];
#pragma unroll
  for (int i = 0; i < 4; ++i)
#pragma unroll
    for (int j = 0; j < 2; ++j)
#pragma unroll
      for (int r = 0; r < 16; ++r) acc[i][j][r] = 0.f;

  const int nt = K >> 6;  // K-tiles, >= 2
  const int arow = wm * 128 + l31;  // + mg*32
  const int brow = wn * 64 + l31;   // + ng*32

  // prologue: stage tiles 0 and 1; wait only tile 0 (vmcnt(8) keeps tile 1 in flight)
  stB(&Bl[0][0], 0, 0); stB(&Bl[0][0], 1, 0);
  stA(&Al[0][0], 0, 0); stA(&Al[0][0], 1, 0);
  stB(&Bl[1][0], 0, 1); stB(&Bl[1][0], 1, 1);
  stA(&Al[1][0], 0, 1); stA(&Al[1][0], 1, 1);
  asm volatile("s_waitcnt vmcnt(8)" ::: "memory");
  __builtin_amdgcn_s_barrier();

  for (int t = 0; t < nt; ++t) {
    const int cur = t & 1;
    const u16* al = &Al[cur][0];
    const u16* bl = &Bl[cur][0];
    // stage tile t+1 into the buffer consumed at t-1 (safe: read done, barrier passed)
    if (t >= 1 && t + 1 < nt) {
      u16* alN = &Al[cur ^ 1][0];
      u16* blN = &Bl[cur ^ 1][0];
      stB(blN, 0, t + 1); stB(blN, 1, t + 1);
      stA(alN, 0, t + 1); stA(alN, 1, t + 1);
    }
    // single scheduling region: 24 ds_read_b128 + 32 MFMA(32x32x16), compiler interleaves
#pragma unroll
    for (int ks = 0; ks < 4; ++ks) {
      frag32_t a[4], b[2];
#pragma unroll
      for (int mg = 0; mg < 4; ++mg) a[mg] = ldsF(al, arow + mg * 32, ks);
#pragma unroll
      for (int ng = 0; ng < 2; ++ng) b[ng] = ldsF(bl, brow + ng * 32, ks);
#pragma unroll
      for (int mg = 0; mg < 4; ++mg)
#pragma unroll
        for (int ng = 0; ng < 2; ++ng)
          acc[mg][ng] = mfma32_bf16(a[mg], b[ng], acc[mg][ng]);
    }
    if (t + 1 < nt) {
      // drains stage(t+1), issued one full compute region ago -> near-free
      asm volatile("s_waitcnt vmcnt(0)" ::: "memory");
      __builtin_amdgcn_s_barrier();
    }
  }

  // epilogue: col = n0 + wn*64 + ng*32 + (lane&31);
  //           row = m0 + wm*128 + mg*32 + (r&3) + 8*(r>>2) + 4*(lane>>5)
  // pack via xor(1)+xor(2): lanes l31%4==0 store 4 cols contiguous (8B bf16 / 16B f32)
  float bvv[2];
#pragma unroll
  for (int ng = 0; ng < 2; ++ng) bvv[ng] = bias[n0 + wn * 64 + ng * 32 + l31];
#pragma unroll
  for (int mg = 0; mg < 4; ++mg) {
#pragma unroll
    for (int ng = 0; ng < 2; ++ng) {
      const int cq = n0 + wn * 64 + ng * 32 + (l31 & 28);  // quad-aligned col
#pragma unroll
      for (int r = 0; r < 16; ++r) {
        const int row = m0 + wm * 128 + mg * 32 + (r & 3) + 8 * (r >> 2) + 4 * lhalf;
        const float val = acc[mg][ng][r] + bvv[ng];
        if constexpr (OUT_BF16) {
          u32 me = f2bf(val);
          u32 d0 = me | (__shfl_xor(me, 1) << 16);  // cols (c, c+1) on even lanes
          u32 d1 = __shfl_xor(d0, 2);               // cols (c+2, c+3) on lane%4==0
          if ((lane & 3) == 0) {
            uint2 o; o.x = d0; o.y = d1;
            *(uint2*)((u16*)Cout + (size_t)row * N + cq) = o;
          }
        } else {
          float v0 = val;
          float v1 = __shfl_xor(v0, 1);
          float v2 = __shfl_xor(v0, 2);
          float v3 = __shfl_xor(v1, 2);
          if ((lane & 3) == 0) {
            float4 o; o.x = v0; o.y = v1; o.z = v2; o.w = v3;
            *(float4*)((float*)Cout + (size_t)row * N + cq) = o;
          }
        }
      }
    }
  }
}

// ---------------- attention (unchanged, passing) ----------------
__global__ __launch_bounds__(256) void attn_kernel(
    const u16* __restrict__ Q, const u16* __restrict__ K,
    const u16* __restrict__ V, u16* __restrict__ O) {
  __shared__ u16 Kl[96][72];
  __shared__ u16 Vt[64][104];

  const int bid = blockIdx.x;
  const int qt = bid & 63;
  const int h = (bid >> 6) & 15;
  const int b = bid >> 10;
  const int tid = threadIdx.x;

#pragma unroll
  for (int it = 0; it < 3; ++it) {
    const int idx = tid + it * 256;
    const int key = idx >> 3, s = idx & 7;
    uint4 val{0u, 0u, 0u, 0u};
    if (key < 77)
      val = *(const uint4*)(K + ((size_t)(b * 77 + key)) * 1024 + h * 64 + s * 8);
    *(uint4*)(&Kl[key][s * 8]) = val;
  }
#pragma unroll
  for (int it = 0; it < 3; ++it) {
    const int idx = tid + it * 256;
    if (idx < 616) {
      const int key = idx >> 3, s = idx & 7;
      const uint4 v4 =
          *(const uint4*)(V + ((size_t)(b * 77 + key)) * 1024 + h * 64 + s * 8);
      const u16* e = (const u16*)&v4;
#pragma unroll
      for (int j = 0; j < 8; ++j) Vt[s * 8 + j][key] = e[j];
    }
  }
#pragma unroll
  for (int it = 0; it < 5; ++it) {
    const int idx = tid + it * 256;
    if (idx < 1216) {
      const int d = idx / 19, kk = 77 + idx % 19;
      Vt[d][kk] = 0;
    }
  }
  __syncthreads();

  const int lane = tid & 63;
  const int wv = tid >> 6;
  const int lr = lane & 15;
  const int lg = lane >> 4;

  const size_t qrow = (size_t)(b * 4096 + qt * 64 + wv * 16 + lr) * 1024 + h * 64;
  frag_t qf[2];
#pragma unroll
  for (int ks = 0; ks < 2; ++ks)
    qf[ks] = *(const frag_t*)(Q + qrow + ks * 32 + lg * 8);

  f32x4 zero4 = {0.f, 0.f, 0.f, 0.f};
  f32x4 sa[5] = {zero4, zero4, zero4, zero4, zero4};
#pragma unroll
  for (int ks = 0; ks < 2; ++ks) {
#pragma unroll
    for (int kt = 0; kt < 5; ++kt) {
      frag_t kf = *(const frag_t*)(&Kl[kt * 16 + lr][ks * 32 + lg * 8]);
      sa[kt] = mfma_bf16(kf, qf[ks], sa[kt]);
    }
  }

  float p[5][4];
  float mx = -3.0e38f;
#pragma unroll
  for (int kt = 0; kt < 5; ++kt)
#pragma unroll
    for (int r = 0; r < 4; ++r) {
      const int key = kt * 16 + lg * 4 + r;
      float s = sa[kt][r] * 0.125f;
      if (key >= 77) s = -3.0e38f;
      p[kt][r] = s;
      mx = fmaxf(mx, s);
    }
  mx = fmaxf(mx, __shfl_xor(mx, 16));
  mx = fmaxf(mx, __shfl_xor(mx, 32));
  float sum = 0.f;
#pragma unroll
  for (int kt = 0; kt < 5; ++kt)
#pragma unroll
    for (int r = 0; r < 4; ++r) {
      const float e = __expf(p[kt][r] - mx);
      p[kt][r] = e;
      sum += e;
    }
  sum += __shfl_xor(sum, 16);
  sum += __shfl_xor(sum, 32);
  const float rden = 1.0f / sum;
#pragma unroll
  for (int kt = 0; kt < 5; ++kt)
#pragma unroll
    for (int r = 0; r < 4; ++r) p[kt][r] *= rden;

  union FP { frag_t v; u16 e[8]; };
  frag_t pa[3];
#pragma unroll
  for (int kb = 0; kb < 3; ++kb) {
    FP f;
#pragma unroll
    for (int j = 0; j < 8; ++j) {
      const int kt = 2 * kb + (j >> 2);
      f.e[j] = (kt < 5) ? f2bf(p[kt][j & 3]) : (u16)0;
    }
    pa[kb] = f.v;
  }

  f32x4 oa[4] = {zero4, zero4, zero4, zero4};
#pragma unroll
  for (int nt = 0; nt < 4; ++nt) {
    const int d = nt * 16 + lr;
#pragma unroll
    for (int kb = 0; kb < 3; ++kb) {
      const int key0 = kb * 32 + lg * 4;
      FP vb;
      *(uint2*)(&vb.e[0]) = *(const uint2*)(&Vt[d][key0]);
      *(uint2*)(&vb.e[4]) = *(const uint2*)(&Vt[d][key0 + 16]);
      oa[nt] = mfma_bf16(pa[kb], vb.v, oa[nt]);
    }
  }

#pragma unroll
  for (int nt = 0; nt < 4; ++nt)
#pragma unroll
    for (int r = 0; r < 4; ++r) {
      const int qr = wv * 16 + lg * 4 + r;
      u32 me = f2bf(oa[nt][r]);
      u32 other = __shfl_xor(me, 1);
      if ((lane & 1) == 0) {
        *(u32*)(O + ((size_t)(b * 4096 + qt * 64 + qr)) * 1024 + h * 64 +
                nt * 16 + lr) = me | (other << 16);
      }
    }
}

// ---------------- launch ----------------
extern "C" void kernel_launch(void* const* d_in, const int* in_sizes, int n_in,
                              void* d_out, int out_size, void* d_ws, size_t ws_size,
                              hipStream_t stream) {
  const float* x  = (const float*)d_in[0];
  const float* p  = (const float*)d_in[1];
  const float* Wq = (const float*)d_in[2];
  const float* bq = (const float*)d_in[3];
  const float* Wk = (const float*)d_in[4];
  const float* bk = (const float*)d_in[5];
  const float* Wv = (const float*)d_in[6];
  const float* bv = (const float*)d_in[7];
  const float* Ww = (const float*)d_in[8];
  const float* bw = (const float*)d_in[9];

  char* ws = (char*)d_ws;
  if (ws_size < 281034752ULL) return;

  u16* x_bf = (u16*)(ws + 0);          // 65536x1024 bf16; reused as attn_out
  u16* q_bf = (u16*)(ws + 134217728);  // 65536x1024
  u16* wq_t = (u16*)(ws + 268435456);  // [1024][1024]
  u16* ww_t = (u16*)(ws + 270532608);  // [1024][1024]
  u16* wk_t = (u16*)(ws + 272629760);  // [1024][512]
  u16* wv_t = (u16*)(ws + 273678336);  // [1024][512]
  u16* p_bf = (u16*)(ws + 274726912);  // 1232x512
  u16* k_bf = (u16*)(ws + 275988480);  // 1232x1024
  u16* v_bf = (u16*)(ws + 278511616);  // 1232x1024

  cast_f32_bf16<<<4096, 256, 0, stream>>>(x, x_bf, 8388608);
  cast_f32_bf16<<<308, 256, 0, stream>>>(p, p_bf, 78848);
  transpose_cast<<<dim3(32, 32), 256, 0, stream>>>(Wq, wq_t, 1024, 1024);
  transpose_cast<<<dim3(32, 32), 256, 0, stream>>>(Ww, ww_t, 1024, 1024);
  transpose_cast<<<dim3(16, 32), 256, 0, stream>>>(Wk, wk_t, 512, 1024);
  transpose_cast<<<dim3(16, 32), 256, 0, stream>>>(Wv, wv_t, 512, 1024);

  // K/V projections (small): 2-phase 128^2 kernel
  gemm_bt<true><<<80, 256, 0, stream>>>(p_bf, wk_t, bk, k_bf, 1232, 1024, 512, 10, 8);
  gemm_bt<true><<<80, 256, 0, stream>>>(p_bf, wv_t, bv, v_bf, 1232, 1024, 512, 10, 8);
  // Q projection: 256^2 single-region 2-phase kernel, 32x32 MFMA (1024 blocks)
  gemm256<true><<<1024, 512, 0, stream>>>(x_bf, wq_t, bq, q_bf, 65536, 1024, 1024);
  // attention
  attn_kernel<<<16384, 256, 0, stream>>>(q_bf, k_bf, v_bf, x_bf);
  // out projection -> fp32
  gemm256<false><<<1024, 512, 0, stream>>>(x_bf, ww_t, bw, d_out, 65536, 1024, 1024);
}